// Round 7
// baseline (404.338 us; speedup 1.0000x reference)
//
#include <hip/hip_runtime.h>

// ---------------------------------------------------------------------------
// GCN, bf16 data-path.
// R15: LAUNCH-COUNT reduction round (13 ops -> 8). Kernel-time sum (~230us)
//   vs total (361us) implies ~130us of inter-dispatch overhead. Fusions:
//   wcvt2 -> extra blocks on hist; scan_tot -> last-block of scan_bucket
//   (fenced done-counter); dummy-row memsets -> gemm epilogues write row M=0;
//   head -> spmm64 epilogue (slot-0 lanes hold full h2 row in regs; 80 FMA vs
//   L1-hot Wl + shfl_xor + lane-0 logsoftmax; h2 round-trip eliminated).
// gemm1 NOTE: five structures all pin at ~60-65us with all counters idle --
//   empirical wall, kept one-shot staging as control.
// spmm128: FETCH=190MB == compulsory 8-XCD minimum; control.
// ---------------------------------------------------------------------------

typedef unsigned short ushort_t;
typedef unsigned int uint_t;
typedef __attribute__((ext_vector_type(8))) short short8;
typedef __attribute__((ext_vector_type(4))) float floatx4;

static __device__ __forceinline__ ushort_t f2bf(float f) {
    union { float f; uint_t u; } c; c.f = f;
    return (ushort_t)((c.u + 0x8000u) >> 16);
}
static __device__ __forceinline__ float bf2f(ushort_t h) {
    union { uint_t u; float f; } c; c.u = ((uint_t)h) << 16;
    return c.f;
}
static __device__ __forceinline__ float2 up2(uint_t p) {
    union { uint_t u; float f; } lo, hi;
    lo.u = p << 16; hi.u = p & 0xffff0000u;
    return make_float2(lo.f, hi.f);
}
static __device__ __forceinline__ uint_t pk2bf(float a, float b) {
    return ((uint_t)f2bf(b) << 16) | (uint_t)f2bf(a);
}
// async global->LDS, 16B per lane; LDS dst = wave-uniform base + lane*16.
static __device__ __forceinline__ void ld_lds16(void* lds, const void* g) {
    __builtin_amdgcn_global_load_lds(
        (const __attribute__((address_space(1))) unsigned int*)g,
        (__attribute__((address_space(3))) unsigned int*)lds, 16, 0, 0);
}

// ------------------------- CSR build (atomic-free) -------------------------
// bucket = dst >> 7  (128 nodes per bucket).  N=100000 -> NB=782 <= NBMAX.
#define NBMAX 800
#define ECAP  4096   // max edges per bucket held in LDS (mean 2046, sigma ~45)

// P1: per-block LDS histogram over buckets (blocks < GB); weight transpose +
// bf16 convert (blocks >= GB). Block GB thread 0 zeroes the done-counter for
// the next kernel's last-block scan.
__global__ __launch_bounds__(256) void hist_kernel(
    const int* __restrict__ dst, int* __restrict__ histG,
    const float* __restrict__ W1, const float* __restrict__ W2,
    ushort_t* __restrict__ W1t, ushort_t* __restrict__ W2t,
    int* __restrict__ done, int E, int NB, int GB) {
    if ((int)blockIdx.x >= GB) {          // ---- fused wcvt2 ----
        if ((int)blockIdx.x == GB && threadIdx.x == 0) *done = 0;
        int i = ((int)blockIdx.x - GB) * 256 + threadIdx.x;
        if (i < 256 * 128) {
            int k = i / 128, n = i % 128;
            W1t[n * 256 + k] = f2bf(W1[i]);
        }
        int j = i - 256 * 128;
        if (j >= 0 && j < 128 * 64) {
            int k = j / 64, n = j % 64;
            W2t[n * 128 + k] = f2bf(W2[j]);
        }
        return;
    }
    __shared__ int h[NBMAX];
    for (int i = threadIdx.x; i < NB; i += 256) h[i] = 0;
    __syncthreads();
    int i16 = (blockIdx.x * 256 + threadIdx.x) * 16;
    if (i16 + 15 < E) {
        #pragma unroll
        for (int u = 0; u < 4; u++) {
            int4 d = *(const int4*)(dst + i16 + u * 4);
            atomicAdd(&h[d.x >> 7], 1);
            atomicAdd(&h[d.y >> 7], 1);
            atomicAdd(&h[d.z >> 7], 1);
            atomicAdd(&h[d.w >> 7], 1);
        }
    } else {
        for (int e = i16; e < E; e++) atomicAdd(&h[dst[e] >> 7], 1);
    }
    __syncthreads();
    int* outp = histG + (size_t)blockIdx.x * NB;   // [blk][b], coalesced
    for (int i = threadIdx.x; i < NB; i += 256) outp[i] = h[i];
}

// S1+S2 fused: per-bucket exclusive scan across blocks (thread-per-bucket,
// coalesced, 16-deep ILP) + LAST-arriving block scans bucket totals -> bbase.
__global__ __launch_bounds__(256) void scan_bucket(
    int* __restrict__ histG, int* __restrict__ totG, int* __restrict__ bbase,
    int* __restrict__ done, int GB, int NB, int nblk) {
    __shared__ int isLast;
    __shared__ int s[256];
    int b = blockIdx.x * 256 + threadIdx.x;
    if (b < NB) {
        int run = 0;
        int g = 0;
        for (; g + 16 <= GB; g += 16) {
            int vv[16];
            #pragma unroll
            for (int u = 0; u < 16; u++) vv[u] = histG[(size_t)(g + u) * NB + b];
            #pragma unroll
            for (int u = 0; u < 16; u++) {
                histG[(size_t)(g + u) * NB + b] = run;
                run += vv[u];
            }
        }
        for (; g < GB; g++) {
            int v = histG[(size_t)g * NB + b];
            histG[(size_t)g * NB + b] = run;
            run += v;
        }
        totG[b] = run;
    }
    __threadfence();                       // release this thread's totG write
    __syncthreads();
    if (threadIdx.x == 0)
        isLast = (atomicAdd(done, 1) == nblk - 1);
    __syncthreads();
    if (!isLast) return;
    __threadfence();                       // acquire other blocks' totG
    int running = 0;
    int nch = (NB + 255) / 256;
    for (int c = 0; c < nch; c++) {
        int j = c * 256 + threadIdx.x;
        int v = (j < NB) ? totG[j] : 0;
        s[threadIdx.x] = v;
        __syncthreads();
        for (int off = 1; off < 256; off <<= 1) {
            int tmp = (threadIdx.x >= off) ? s[threadIdx.x - off] : 0;
            __syncthreads();
            s[threadIdx.x] += tmp;
            __syncthreads();
        }
        if (j < NB) bbase[j] = s[threadIdx.x] - v + running;
        int ctot = s[255];
        __syncthreads();
        running += ctot;
    }
    if (threadIdx.x == 0) bbase[NB] = running;
}

// P3: scatter edges into bucket-grouped order. Same block/edge mapping as P1,
// positions come from LDS atomicAdd on this block's reserved ranges.
// packed = src | (dst&127)<<17   (src < 2^17, dl 7 bits).
__global__ __launch_bounds__(256) void scatter_kernel(
    const int* __restrict__ src, const int* __restrict__ dst,
    const int* __restrict__ histG, const int* __restrict__ bbase,
    int* __restrict__ packed, int E, int NB) {
    __shared__ int lbase[NBMAX];
    const int* row = histG + (size_t)blockIdx.x * NB;
    for (int i = threadIdx.x; i < NB; i += 256)
        lbase[i] = bbase[i] + row[i];
    __syncthreads();
    int i16 = (blockIdx.x * 256 + threadIdx.x) * 16;
    if (i16 + 15 < E) {
        #pragma unroll
        for (int u = 0; u < 4; u++) {
            int4 s4 = *(const int4*)(src + i16 + u * 4);
            int4 d4 = *(const int4*)(dst + i16 + u * 4);
            int p;
            p = atomicAdd(&lbase[d4.x >> 7], 1); packed[p] = s4.x | ((d4.x & 127) << 17);
            p = atomicAdd(&lbase[d4.y >> 7], 1); packed[p] = s4.y | ((d4.y & 127) << 17);
            p = atomicAdd(&lbase[d4.z >> 7], 1); packed[p] = s4.z | ((d4.z & 127) << 17);
            p = atomicAdd(&lbase[d4.w >> 7], 1); packed[p] = s4.w | ((d4.w & 127) << 17);
        }
    } else {
        for (int e = i16; e < E; e++) {
            int d = dst[e];
            int p = atomicAdd(&lbase[d >> 7], 1);
            packed[p] = src[e] | ((d & 127) << 17);
        }
    }
}

// P4: one block per bucket. Edges to LDS, count 128 node degrees (dinv fused),
// 128-wide scan -> rowptr, second pass -> csr. rowptr[N]=E falls out of the
// last bucket (nodes >= N have zero count).
__global__ __launch_bounds__(256) void bucket_csr(
    const int* __restrict__ packed, const int* __restrict__ bbase,
    int* __restrict__ rowptr, int* __restrict__ csr,
    float* __restrict__ dinv, int N, int NB) {
    __shared__ int ebuf[ECAP];
    __shared__ int cnt[128];
    __shared__ int pl[128];
    __shared__ int s[256];
    const int b = blockIdx.x;
    const int t = threadIdx.x;
    const int lo = bbase[b];
    const int hi = bbase[b + 1];
    int m = hi - lo;
    if (m > ECAP) m = ECAP;   // statistically unreachable (+45 sigma)
    for (int i = t; i < m; i += 256) ebuf[i] = packed[lo + i];
    if (t < 128) cnt[t] = 0;
    __syncthreads();
    for (int i = t; i < m; i += 256) atomicAdd(&cnt[ebuf[i] >> 17], 1);
    __syncthreads();
    const int node0 = b << 7;
    int c = (t < 128) ? cnt[t] : 0;
    if (t < 128 && node0 + t < N)
        dinv[node0 + t] = rsqrtf((float)(c + 1));   // +1 self loop
    s[t] = c;
    __syncthreads();
    for (int off = 1; off < 256; off <<= 1) {
        int tmp = (t >= off) ? s[t - off] : 0;
        __syncthreads();
        s[t] += tmp;
        __syncthreads();
    }
    int excl = s[t] - c;
    if (t < 128) {
        pl[t] = excl;
        if (node0 + t <= N) rowptr[node0 + t] = lo + excl;
    }
    __syncthreads();
    for (int i = t; i < m; i += 256) {
        int e = ebuf[i];
        int p = atomicAdd(&pl[e >> 17], 1);
        csr[lo + p] = e & 0x1FFFF;
    }
}

// ------------------------------ GEMM 1 -------------------------------------
// A fp32 [M,256], Bt bf16 [128,256]; out bf16 [M,128] scaled by dinv.
// One-shot full-K staging (R14): A-tile 64KB + B 64KB, single barrier, pure
// LDS+MFMA. Epilogue also zeroes dummy row M (replaces memset).
__global__ __launch_bounds__(256) void gemm1_mfma(
    const float* __restrict__ A, const ushort_t* __restrict__ Bt,
    const float* __restrict__ dinv, ushort_t* __restrict__ out, int M) {
    __shared__ float    As[64 * 256];    // 64 KB
    __shared__ ushort_t Bs[128 * 256];   // 64 KB
    const int tid = threadIdx.x;
    const int l = tid & 63;
    const int wave = tid >> 6;
    const int lrow = l & 15, hh = l >> 4;
    const int m0 = blockIdx.x * 64;

    #pragma unroll
    for (int rd = 0; rd < 16; rd++) {
        int idx = rd * 256 + tid;
        int r = idx >> 6, cs = idx & 63;
        int row = m0 + r; if (row >= M) row = M - 1;
        int cl = cs ^ (r & 7);
        ld_lds16(&As[idx * 4], A + (size_t)row * 256 + cl * 4);
    }
    #pragma unroll
    for (int rd = 0; rd < 16; rd++) {
        int idx = rd * 256 + tid;
        int n = idx >> 5, cs = idx & 31;
        int cl = cs ^ (n & 7);
        ld_lds16(&Bs[idx * 8], Bt + (size_t)n * 256 + cl * 8);
    }
    __syncthreads();

    floatx4 acc[8];
    #pragma unroll
    for (int nt = 0; nt < 8; nt++)
        acc[nt] = (floatx4){0.f, 0.f, 0.f, 0.f};

    const int wr = wave * 16 + lrow;
    #pragma unroll
    for (int kk = 0; kk < 8; kk++) {
        int c0 = kk * 8 + hh * 2;
        float4 u = *(const float4*)&As[wr * 256 + ((c0    ) ^ (wr & 7)) * 4];
        float4 v = *(const float4*)&As[wr * 256 + ((c0 + 1) ^ (wr & 7)) * 4];
        short8 afr;
        afr[0] = (short)f2bf(u.x); afr[1] = (short)f2bf(u.y);
        afr[2] = (short)f2bf(u.z); afr[3] = (short)f2bf(u.w);
        afr[4] = (short)f2bf(v.x); afr[5] = (short)f2bf(v.y);
        afr[6] = (short)f2bf(v.z); afr[7] = (short)f2bf(v.w);
        short8 bfr[8];
        #pragma unroll
        for (int nt = 0; nt < 8; nt++) {
            int n = nt * 16 + lrow;
            int c = kk * 4 + hh;
            bfr[nt] = *(const short8*)&Bs[n * 256 + (c ^ (n & 7)) * 8];
        }
        #pragma unroll
        for (int nt = 0; nt < 8; nt++)
            acc[nt] = __builtin_amdgcn_mfma_f32_16x16x32_bf16(
                afr, bfr[nt], acc[nt], 0, 0, 0);
    }

    const int mbase = m0 + wave * 16 + hh * 4;
    float4 dv = *(const float4*)&dinv[mbase];   // dinv padded past N
    float d[4] = {dv.x, dv.y, dv.z, dv.w};
    #pragma unroll
    for (int i = 0; i < 4; i++) {
        int m = mbase + i;
        if (m < M) {
            #pragma unroll
            for (int nt = 0; nt < 8; nt++)
                out[(size_t)m * 128 + nt * 16 + lrow] =
                    f2bf(acc[nt][i] * d[i]);
        } else if (m == M) {               // zero dummy row (was memset)
            #pragma unroll
            for (int nt = 0; nt < 8; nt++)
                out[(size_t)M * 128 + nt * 16 + lrow] = 0;
        }
    }
}

// ------------------------------ GEMM 2 -------------------------------------
// A bf16 [M,128], Bt bf16 [64,128]; out bf16 [M,64] scaled by dinv.
// One-shot template: 32KB LDS. Epilogue zeroes dummy row M.
__global__ __launch_bounds__(256) void gemm2_mfma(
    const ushort_t* __restrict__ A, const ushort_t* __restrict__ Bt,
    const float* __restrict__ dinv, ushort_t* __restrict__ out, int M) {
    __shared__ ushort_t As[64 * 128];   // 16 KB
    __shared__ ushort_t Bs[64 * 128];   // 16 KB
    const int tid = threadIdx.x;
    const int l = tid & 63;
    const int wave = tid >> 6;
    const int lrow = l & 15, hh = l >> 4;
    const int m0 = blockIdx.x * 64;

    #pragma unroll
    for (int rd = 0; rd < 4; rd++) {
        int idx = rd * 256 + tid;
        int r = idx >> 4, cs = idx & 15;
        int row = m0 + r; if (row >= M) row = M - 1;
        int cl = cs ^ (r & 7);
        ld_lds16(&As[idx * 8], A + (size_t)row * 128 + cl * 8);
    }
    #pragma unroll
    for (int rd = 0; rd < 4; rd++) {
        int idx = rd * 256 + tid;
        int n = idx >> 4, cs = idx & 15;
        int cl = cs ^ (n & 7);
        ld_lds16(&Bs[idx * 8], Bt + (size_t)n * 128 + cl * 8);
    }
    __syncthreads();

    floatx4 acc[4];
    #pragma unroll
    for (int nt = 0; nt < 4; nt++)
        acc[nt] = (floatx4){0.f, 0.f, 0.f, 0.f};

    const int wr = wave * 16 + lrow;
    #pragma unroll
    for (int kk = 0; kk < 4; kk++) {
        int c0 = kk * 4 + hh;
        short8 afr = *(const short8*)&As[wr * 128 + (c0 ^ (wr & 7)) * 8];
        short8 bfr[4];
        #pragma unroll
        for (int nt = 0; nt < 4; nt++) {
            int n = nt * 16 + lrow;
            bfr[nt] = *(const short8*)&Bs[n * 128 + (c0 ^ (n & 7)) * 8];
        }
        #pragma unroll
        for (int nt = 0; nt < 4; nt++)
            acc[nt] = __builtin_amdgcn_mfma_f32_16x16x32_bf16(
                afr, bfr[nt], acc[nt], 0, 0, 0);
    }

    const int mbase = m0 + wave * 16 + hh * 4;
    float4 dv = *(const float4*)&dinv[mbase];
    float d[4] = {dv.x, dv.y, dv.z, dv.w};
    #pragma unroll
    for (int i = 0; i < 4; i++) {
        int m = mbase + i;
        if (m < M) {
            #pragma unroll
            for (int nt = 0; nt < 4; nt++)
                out[(size_t)m * 64 + nt * 16 + lrow] =
                    f2bf(acc[nt][i] * d[i]);
        } else if (m == M) {               // zero dummy row (was memset)
            #pragma unroll
            for (int nt = 0; nt < 4; nt++)
                out[(size_t)M * 64 + nt * 16 + lrow] = 0;
        }
    }
}

// ------------------------------ SpMM 1 -------------------------------------
// F=128, bf16 in/out. Multi-edge dwordx4 gather: 16 lanes cover one 256B row,
// 4 edges per load instruction. doff = byte offset of zeroed dummy row.
__global__ __launch_bounds__(256) void spmm_relu128(
    const ushort_t* __restrict__ Mm, const int* __restrict__ rowptr,
    const int* __restrict__ csr, const float* __restrict__ dinv,
    const float* __restrict__ bias, ushort_t* __restrict__ out, int n, int doff) {
    int v = (blockIdx.x * 256 + threadIdx.x) >> 6;
    int lane = threadIdx.x & 63;
    if (v >= n) return;
    int jb = rowptr[v];
    int cntn = rowptr[v + 1] - jb;
    const char* Mb = (const char*)Mm;
    const int slot = lane >> 4;             // which of 4 edges per instr
    const int q = lane & 15;                // column group: bytes q*16 (8 cols)
    const uint_t qb = (uint_t)q * 16;

    float2 a0 = {0.f, 0.f}, a1 = a0, a2 = a0, a3 = a0;
    if (slot == 0) {                        // self row, counted once
        uint4 s = *(const uint4*)(Mb + ((size_t)v << 8) + qb);
        a0 = up2(s.x); a1 = up2(s.y); a2 = up2(s.z); a3 = up2(s.w);
    }

    for (int base = 0; base < cntn; base += 64) {
        int m = cntn - base; if (m > 64) m = 64;
        int roff = (base + lane < cntn) ? (csr[jb + base + lane] << 8) : doff;
        int m4 = (m + 3) & ~3;
        int jj = 0;
        for (; jj + 16 <= m4; jj += 16) {   // 4 x dwordx4 = 16 edges
            uint_t o[4];
            #pragma unroll
            for (int t = 0; t < 4; t++)
                o[t] = (uint_t)__shfl(roff, jj + 4 * t + slot) + qb;
            uint4 p[4];
            #pragma unroll
            for (int t = 0; t < 4; t++) p[t] = *(const uint4*)(Mb + o[t]);
            #pragma unroll
            for (int t = 0; t < 4; t++) {
                float2 f;
                f = up2(p[t].x); a0.x += f.x; a0.y += f.y;
                f = up2(p[t].y); a1.x += f.x; a1.y += f.y;
                f = up2(p[t].z); a2.x += f.x; a2.y += f.y;
                f = up2(p[t].w); a3.x += f.x; a3.y += f.y;
            }
        }
        for (; jj < m4; jj += 4) {          // 1 x dwordx4 = 4 edges
            uint_t o = (uint_t)__shfl(roff, jj + slot) + qb;
            uint4 p = *(const uint4*)(Mb + o);
            float2 f;
            f = up2(p.x); a0.x += f.x; a0.y += f.y;
            f = up2(p.y); a1.x += f.x; a1.y += f.y;
            f = up2(p.z); a2.x += f.x; a2.y += f.y;
            f = up2(p.w); a3.x += f.x; a3.y += f.y;
        }
    }
    float r[8] = {a0.x, a0.y, a1.x, a1.y, a2.x, a2.y, a3.x, a3.y};
    #pragma unroll
    for (int i = 0; i < 8; i++) r[i] += __shfl_xor(r[i], 16);
    #pragma unroll
    for (int i = 0; i < 8; i++) r[i] += __shfl_xor(r[i], 32);
    if (slot == 0) {
        float d = dinv[v];
        float4 bv0 = *(const float4*)&bias[q * 8];
        float4 bv1 = *(const float4*)&bias[q * 8 + 4];
        float o0 = fmaxf(d * r[0] + bv0.x, 0.f);
        float o1 = fmaxf(d * r[1] + bv0.y, 0.f);
        float o2 = fmaxf(d * r[2] + bv0.z, 0.f);
        float o3 = fmaxf(d * r[3] + bv0.w, 0.f);
        float o4 = fmaxf(d * r[4] + bv1.x, 0.f);
        float o5 = fmaxf(d * r[5] + bv1.y, 0.f);
        float o6 = fmaxf(d * r[6] + bv1.z, 0.f);
        float o7 = fmaxf(d * r[7] + bv1.w, 0.f);
        uint4 pk;
        pk.x = pk2bf(o0, o1); pk.y = pk2bf(o2, o3);
        pk.z = pk2bf(o4, o5); pk.w = pk2bf(o6, o7);
        *(uint4*)(out + (size_t)v * 128 + q * 8) = pk;
    }
}

// ------------------------ SpMM 2 + head (fused) ----------------------------
// F=64, bf16 in. 8 lanes cover one 128B row, 8 edges per load. After the
// slot-reduction, slot-0 lanes (q=0..7) hold the full h2 row in registers:
// apply relu+bias, then head matvec (Wl 64x10, L1-hot), 3x shfl_xor sum,
// lane-0 log-softmax -> out fp32 [n,10]. h2 never materialized.
__global__ __launch_bounds__(256) void spmm64_head(
    const ushort_t* __restrict__ Mm, const int* __restrict__ rowptr,
    const int* __restrict__ csr, const float* __restrict__ dinv,
    const float* __restrict__ bias, const float* __restrict__ Wl,
    const float* __restrict__ bl, float* __restrict__ out, int n, int doff) {
    int v = (blockIdx.x * 256 + threadIdx.x) >> 6;
    int lane = threadIdx.x & 63;
    if (v >= n) return;
    int jb = rowptr[v];
    int cntn = rowptr[v + 1] - jb;
    const char* Mb = (const char*)Mm;
    const int slot = lane >> 3;             // which of 8 edges per instr
    const int q = lane & 7;                 // column group: bytes q*16 (8 cols)
    const uint_t qb = (uint_t)q * 16;

    float2 a0 = {0.f, 0.f}, a1 = a0, a2 = a0, a3 = a0;
    if (slot == 0) {                        // self row
        uint4 s = *(const uint4*)(Mb + ((size_t)v << 7) + qb);
        a0 = up2(s.x); a1 = up2(s.y); a2 = up2(s.z); a3 = up2(s.w);
    }

    for (int base = 0; base < cntn; base += 64) {
        int m = cntn - base; if (m > 64) m = 64;
        int roff = (base + lane < cntn) ? (csr[jb + base + lane] << 7) : doff;
        int m8 = (m + 7) & ~7;
        int jj = 0;
        for (; jj + 16 <= m8; jj += 16) {   // 2 x dwordx4 = 16 edges
            uint_t o[2];
            #pragma unroll
            for (int t = 0; t < 2; t++)
                o[t] = (uint_t)__shfl(roff, jj + 8 * t + slot) + qb;
            uint4 p[2];
            #pragma unroll
            for (int t = 0; t < 2; t++) p[t] = *(const uint4*)(Mb + o[t]);
            #pragma unroll
            for (int t = 0; t < 2; t++) {
                float2 f;
                f = up2(p[t].x); a0.x += f.x; a0.y += f.y;
                f = up2(p[t].y); a1.x += f.x; a1.y += f.y;
                f = up2(p[t].z); a2.x += f.x; a2.y += f.y;
                f = up2(p[t].w); a3.x += f.x; a3.y += f.y;
            }
        }
        for (; jj < m8; jj += 8) {          // 1 x dwordx4 = 8 edges
            uint_t o = (uint_t)__shfl(roff, jj + slot) + qb;
            uint4 p = *(const uint4*)(Mb + o);
            float2 f;
            f = up2(p.x); a0.x += f.x; a0.y += f.y;
            f = up2(p.y); a1.x += f.x; a1.y += f.y;
            f = up2(p.z); a2.x += f.x; a2.y += f.y;
            f = up2(p.w); a3.x += f.x; a3.y += f.y;
        }
    }
    float r[8] = {a0.x, a0.y, a1.x, a1.y, a2.x, a2.y, a3.x, a3.y};
    #pragma unroll
    for (int i = 0; i < 8; i++) r[i] += __shfl_xor(r[i], 8);
    #pragma unroll
    for (int i = 0; i < 8; i++) r[i] += __shfl_xor(r[i], 16);
    #pragma unroll
    for (int i = 0; i < 8; i++) r[i] += __shfl_xor(r[i], 32);
    if (slot == 0) {                        // lanes 0..7 hold full h2 row
        float d = dinv[v];
        float4 bv0 = *(const float4*)&bias[q * 8];
        float4 bv1 = *(const float4*)&bias[q * 8 + 4];
        float h[8];
        h[0] = fmaxf(d * r[0] + bv0.x, 0.f);
        h[1] = fmaxf(d * r[1] + bv0.y, 0.f);
        h[2] = fmaxf(d * r[2] + bv0.z, 0.f);
        h[3] = fmaxf(d * r[3] + bv0.w, 0.f);
        h[4] = fmaxf(d * r[4] + bv1.x, 0.f);
        h[5] = fmaxf(d * r[5] + bv1.y, 0.f);
        h[6] = fmaxf(d * r[6] + bv1.z, 0.f);
        h[7] = fmaxf(d * r[7] + bv1.w, 0.f);
        float lg[10];
        #pragma unroll
        for (int c = 0; c < 10; c++) lg[c] = 0.f;
        #pragma unroll
        for (int i = 0; i < 8; i++) {
            const float* wrow = &Wl[(q * 8 + i) * 10];
            #pragma unroll
            for (int c = 0; c < 10; c++) lg[c] += h[i] * wrow[c];
        }
        #pragma unroll
        for (int c = 0; c < 10; c++) {
            lg[c] += __shfl_xor(lg[c], 1);
            lg[c] += __shfl_xor(lg[c], 2);
            lg[c] += __shfl_xor(lg[c], 4);
        }
        if (q == 0) {
            #pragma unroll
            for (int c = 0; c < 10; c++) lg[c] += bl[c];
            float mx = lg[0];
            #pragma unroll
            for (int c = 1; c < 10; c++) mx = fmaxf(mx, lg[c]);
            float s = 0.f;
            #pragma unroll
            for (int c = 0; c < 10; c++) s += expf(lg[c] - mx);
            float lse = logf(s);
            #pragma unroll
            for (int c = 0; c < 10; c++)
                out[(size_t)v * 10 + c] = lg[c] - mx - lse;
        }
    }
}

// ------------------------------ launch -------------------------------------
extern "C" void kernel_launch(void* const* d_in, const int* in_sizes, int n_in,
                              void* d_out, int out_size, void* d_ws, size_t ws_size,
                              hipStream_t stream) {
    const float* x   = (const float*)d_in[0];
    const int*   ei  = (const int*)d_in[1];      // int32 (JAX x64 disabled)
    const float* W1  = (const float*)d_in[2];
    const float* b1  = (const float*)d_in[3];
    const float* W2  = (const float*)d_in[4];
    const float* b2  = (const float*)d_in[5];
    const float* Wl  = (const float*)d_in[6];
    const float* bl  = (const float*)d_in[7];
    float*       out = (float*)d_out;

    const int N = in_sizes[0] / 256;   // 100000
    const int E = in_sizes[1] / 2;     // 1600000
    const int* srcI = ei;
    const int* dstI = ei + E;

    const int NB = (N + 127) >> 7;      // 782 buckets (<= NBMAX)
    const int GB = (E + 4095) / 4096;   // 391 edge blocks, 16 edges/thread
    const int WB = (256 * 128 + 128 * 64 + 255) / 256;  // 160 wcvt blocks
    const int SB = (NB + 255) / 256;    // scan_bucket blocks

    char* ws = (char*)d_ws;
    size_t off = 0;
    auto alloc = [&](size_t bytes) -> void* {
        void* p = ws + off;
        off = (off + bytes + 255) & ~(size_t)255;
        return p;
    };
    int*      histG  = (int*)alloc((size_t)GB * NB * 4);      // ~1.2 MB
    int*      totG   = (int*)alloc((size_t)NB * 4);
    int*      bbase  = (int*)alloc((size_t)(NB + 1) * 4);
    int*      done   = (int*)alloc(256);
    int*      packed = (int*)alloc((size_t)E * 4);            // bucket-grouped edges
    int*      rowptr = (int*)alloc((size_t)(N + 1) * 4);
    float*    dinv   = (float*)alloc((size_t)(N + 128) * 4);  // padded: epilogue float4
    int*      csr    = (int*)alloc((size_t)E * 4);
    ushort_t* W1t    = (ushort_t*)alloc((size_t)128 * 256 * 2);
    ushort_t* W2t    = (ushort_t*)alloc((size_t)64 * 128 * 2);
    ushort_t* bufA   = (ushort_t*)alloc((size_t)(N + 2) * 128 * 2); // M1'/M2' + dummy row
    ushort_t* bufB   = (ushort_t*)alloc((size_t)N * 128 * 2); // h1 (bf16)

    // ---- atomic-free CSR build (+fused wcvt, +fused totals scan) ----
    hist_kernel<<<GB + WB, 256, 0, stream>>>(dstI, histG, W1, W2, W1t, W2t,
                                             done, E, NB, GB);
    scan_bucket<<<SB, 256, 0, stream>>>(histG, totG, bbase, done, GB, NB, SB);
    scatter_kernel<<<GB, 256, 0, stream>>>(srcI, dstI, histG, bbase, packed, E, NB);
    bucket_csr<<<NB, 256, 0, stream>>>(packed, bbase, rowptr, csr, dinv, N, NB);

    const int gblk = (N + 63) / 64;    // 64 rows per block
    // layer 1 (gemm1 epilogue zeroes dummy row N)
    gemm1_mfma<<<gblk, 256, 0, stream>>>(x, W1t, dinv, bufA, N);
    spmm_relu128<<<(N + 3) / 4, 256, 0, stream>>>(bufA, rowptr, csr, dinv, b1, bufB, N, N << 8);
    // layer 2 (gemm2 epilogue zeroes dummy row N)
    gemm2_mfma<<<gblk, 256, 0, stream>>>(bufB, W2t, dinv, bufA, N);
    // spmm2 + head fused: writes final log-softmax
    spmm64_head<<<(N + 3) / 4, 256, 0, stream>>>(bufA, rowptr, csr, dinv, b2,
                                                 Wl, bl, out, N, N << 7);
}

// Round 8
// 358.440 us; speedup vs baseline: 1.1280x; 1.1280x over previous
//
#include <hip/hip_runtime.h>

// ---------------------------------------------------------------------------
// GCN, bf16 data-path.
// R16: REVERT R15's head fusion -- it put the head matvec wave-per-node
//   (125 instr/node) on spmm64's critical path vs thread-per-node (~10
//   instr/node) in the standalone head kernel: spmm64_head=107us vs 49+8
//   split. KEEP R15's harmless fusions (wcvt-in-hist, scan_tot-in-
//   scan_bucket, epilogue dummy-row zeroing): R15 A/B calibrated launch
//   overhead at ~1.4us/op, so these are worth ~-7us net.
// Known walls (controls): gemm1 62us -- five structures (LDS-dbuf /
//   reg-staged / direct 32r/16r / one-shot full-K) all pin at 60-65us with
//   every counter idle (occ 8-31%, MfmaUtil ~3.5%, VALU <10%, HBM ~15%).
//   spmm128 62us -- FETCH 190MB == compulsory 8-XCD minimum (25.6MB x 8).
// ---------------------------------------------------------------------------

typedef unsigned short ushort_t;
typedef unsigned int uint_t;
typedef __attribute__((ext_vector_type(8))) short short8;
typedef __attribute__((ext_vector_type(4))) float floatx4;

static __device__ __forceinline__ ushort_t f2bf(float f) {
    union { float f; uint_t u; } c; c.f = f;
    return (ushort_t)((c.u + 0x8000u) >> 16);
}
static __device__ __forceinline__ float bf2f(ushort_t h) {
    union { uint_t u; float f; } c; c.u = ((uint_t)h) << 16;
    return c.f;
}
static __device__ __forceinline__ float2 up2(uint_t p) {
    union { uint_t u; float f; } lo, hi;
    lo.u = p << 16; hi.u = p & 0xffff0000u;
    return make_float2(lo.f, hi.f);
}
static __device__ __forceinline__ uint_t pk2bf(float a, float b) {
    return ((uint_t)f2bf(b) << 16) | (uint_t)f2bf(a);
}
// async global->LDS, 16B per lane; LDS dst = wave-uniform base + lane*16.
static __device__ __forceinline__ void ld_lds16(void* lds, const void* g) {
    __builtin_amdgcn_global_load_lds(
        (const __attribute__((address_space(1))) unsigned int*)g,
        (__attribute__((address_space(3))) unsigned int*)lds, 16, 0, 0);
}

// ------------------------- CSR build (atomic-free) -------------------------
// bucket = dst >> 7  (128 nodes per bucket).  N=100000 -> NB=782 <= NBMAX.
#define NBMAX 800
#define ECAP  4096   // max edges per bucket held in LDS (mean 2046, sigma ~45)

// P1: per-block LDS histogram over buckets (blocks < GB); weight transpose +
// bf16 convert (blocks >= GB). Block GB thread 0 zeroes the done-counter.
__global__ __launch_bounds__(256) void hist_kernel(
    const int* __restrict__ dst, int* __restrict__ histG,
    const float* __restrict__ W1, const float* __restrict__ W2,
    ushort_t* __restrict__ W1t, ushort_t* __restrict__ W2t,
    int* __restrict__ done, int E, int NB, int GB) {
    if ((int)blockIdx.x >= GB) {          // ---- fused wcvt2 ----
        if ((int)blockIdx.x == GB && threadIdx.x == 0) *done = 0;
        int i = ((int)blockIdx.x - GB) * 256 + threadIdx.x;
        if (i < 256 * 128) {
            int k = i / 128, n = i % 128;
            W1t[n * 256 + k] = f2bf(W1[i]);
        }
        int j = i - 256 * 128;
        if (j >= 0 && j < 128 * 64) {
            int k = j / 64, n = j % 64;
            W2t[n * 128 + k] = f2bf(W2[j]);
        }
        return;
    }
    __shared__ int h[NBMAX];
    for (int i = threadIdx.x; i < NB; i += 256) h[i] = 0;
    __syncthreads();
    int i16 = (blockIdx.x * 256 + threadIdx.x) * 16;
    if (i16 + 15 < E) {
        #pragma unroll
        for (int u = 0; u < 4; u++) {
            int4 d = *(const int4*)(dst + i16 + u * 4);
            atomicAdd(&h[d.x >> 7], 1);
            atomicAdd(&h[d.y >> 7], 1);
            atomicAdd(&h[d.z >> 7], 1);
            atomicAdd(&h[d.w >> 7], 1);
        }
    } else {
        for (int e = i16; e < E; e++) atomicAdd(&h[dst[e] >> 7], 1);
    }
    __syncthreads();
    int* outp = histG + (size_t)blockIdx.x * NB;   // [blk][b], coalesced
    for (int i = threadIdx.x; i < NB; i += 256) outp[i] = h[i];
}

// S1+S2 fused: per-bucket exclusive scan across blocks (thread-per-bucket,
// coalesced, 16-deep ILP) + LAST-arriving block scans bucket totals -> bbase.
__global__ __launch_bounds__(256) void scan_bucket(
    int* __restrict__ histG, int* __restrict__ totG, int* __restrict__ bbase,
    int* __restrict__ done, int GB, int NB, int nblk) {
    __shared__ int isLast;
    __shared__ int s[256];
    int b = blockIdx.x * 256 + threadIdx.x;
    if (b < NB) {
        int run = 0;
        int g = 0;
        for (; g + 16 <= GB; g += 16) {
            int vv[16];
            #pragma unroll
            for (int u = 0; u < 16; u++) vv[u] = histG[(size_t)(g + u) * NB + b];
            #pragma unroll
            for (int u = 0; u < 16; u++) {
                histG[(size_t)(g + u) * NB + b] = run;
                run += vv[u];
            }
        }
        for (; g < GB; g++) {
            int v = histG[(size_t)g * NB + b];
            histG[(size_t)g * NB + b] = run;
            run += v;
        }
        totG[b] = run;
    }
    __threadfence();                       // release this thread's totG write
    __syncthreads();
    if (threadIdx.x == 0)
        isLast = (atomicAdd(done, 1) == nblk - 1);
    __syncthreads();
    if (!isLast) return;
    __threadfence();                       // acquire other blocks' totG
    int running = 0;
    int nch = (NB + 255) / 256;
    for (int c = 0; c < nch; c++) {
        int j = c * 256 + threadIdx.x;
        int v = (j < NB) ? totG[j] : 0;
        s[threadIdx.x] = v;
        __syncthreads();
        for (int off = 1; off < 256; off <<= 1) {
            int tmp = (threadIdx.x >= off) ? s[threadIdx.x - off] : 0;
            __syncthreads();
            s[threadIdx.x] += tmp;
            __syncthreads();
        }
        if (j < NB) bbase[j] = s[threadIdx.x] - v + running;
        int ctot = s[255];
        __syncthreads();
        running += ctot;
    }
    if (threadIdx.x == 0) bbase[NB] = running;
}

// P3: scatter edges into bucket-grouped order. Same block/edge mapping as P1,
// positions come from LDS atomicAdd on this block's reserved ranges.
// packed = src | (dst&127)<<17   (src < 2^17, dl 7 bits).
__global__ __launch_bounds__(256) void scatter_kernel(
    const int* __restrict__ src, const int* __restrict__ dst,
    const int* __restrict__ histG, const int* __restrict__ bbase,
    int* __restrict__ packed, int E, int NB) {
    __shared__ int lbase[NBMAX];
    const int* row = histG + (size_t)blockIdx.x * NB;
    for (int i = threadIdx.x; i < NB; i += 256)
        lbase[i] = bbase[i] + row[i];
    __syncthreads();
    int i16 = (blockIdx.x * 256 + threadIdx.x) * 16;
    if (i16 + 15 < E) {
        #pragma unroll
        for (int u = 0; u < 4; u++) {
            int4 s4 = *(const int4*)(src + i16 + u * 4);
            int4 d4 = *(const int4*)(dst + i16 + u * 4);
            int p;
            p = atomicAdd(&lbase[d4.x >> 7], 1); packed[p] = s4.x | ((d4.x & 127) << 17);
            p = atomicAdd(&lbase[d4.y >> 7], 1); packed[p] = s4.y | ((d4.y & 127) << 17);
            p = atomicAdd(&lbase[d4.z >> 7], 1); packed[p] = s4.z | ((d4.z & 127) << 17);
            p = atomicAdd(&lbase[d4.w >> 7], 1); packed[p] = s4.w | ((d4.w & 127) << 17);
        }
    } else {
        for (int e = i16; e < E; e++) {
            int d = dst[e];
            int p = atomicAdd(&lbase[d >> 7], 1);
            packed[p] = src[e] | ((d & 127) << 17);
        }
    }
}

// P4: one block per bucket. Edges to LDS, count 128 node degrees (dinv fused),
// 128-wide scan -> rowptr, second pass -> csr. rowptr[N]=E falls out of the
// last bucket (nodes >= N have zero count).
__global__ __launch_bounds__(256) void bucket_csr(
    const int* __restrict__ packed, const int* __restrict__ bbase,
    int* __restrict__ rowptr, int* __restrict__ csr,
    float* __restrict__ dinv, int N, int NB) {
    __shared__ int ebuf[ECAP];
    __shared__ int cnt[128];
    __shared__ int pl[128];
    __shared__ int s[256];
    const int b = blockIdx.x;
    const int t = threadIdx.x;
    const int lo = bbase[b];
    const int hi = bbase[b + 1];
    int m = hi - lo;
    if (m > ECAP) m = ECAP;   // statistically unreachable (+45 sigma)
    for (int i = t; i < m; i += 256) ebuf[i] = packed[lo + i];
    if (t < 128) cnt[t] = 0;
    __syncthreads();
    for (int i = t; i < m; i += 256) atomicAdd(&cnt[ebuf[i] >> 17], 1);
    __syncthreads();
    const int node0 = b << 7;
    int c = (t < 128) ? cnt[t] : 0;
    if (t < 128 && node0 + t < N)
        dinv[node0 + t] = rsqrtf((float)(c + 1));   // +1 self loop
    s[t] = c;
    __syncthreads();
    for (int off = 1; off < 256; off <<= 1) {
        int tmp = (t >= off) ? s[t - off] : 0;
        __syncthreads();
        s[t] += tmp;
        __syncthreads();
    }
    int excl = s[t] - c;
    if (t < 128) {
        pl[t] = excl;
        if (node0 + t <= N) rowptr[node0 + t] = lo + excl;
    }
    __syncthreads();
    for (int i = t; i < m; i += 256) {
        int e = ebuf[i];
        int p = atomicAdd(&pl[e >> 17], 1);
        csr[lo + p] = e & 0x1FFFF;
    }
}

// ------------------------------ GEMM 1 -------------------------------------
// A fp32 [M,256], Bt bf16 [128,256]; out bf16 [M,128] scaled by dinv.
// One-shot full-K staging (R14): A-tile 64KB + B 64KB, single barrier, pure
// LDS+MFMA. Epilogue also zeroes dummy row M (replaces memset).
__global__ __launch_bounds__(256) void gemm1_mfma(
    const float* __restrict__ A, const ushort_t* __restrict__ Bt,
    const float* __restrict__ dinv, ushort_t* __restrict__ out, int M) {
    __shared__ float    As[64 * 256];    // 64 KB
    __shared__ ushort_t Bs[128 * 256];   // 64 KB
    const int tid = threadIdx.x;
    const int l = tid & 63;
    const int wave = tid >> 6;
    const int lrow = l & 15, hh = l >> 4;
    const int m0 = blockIdx.x * 64;

    #pragma unroll
    for (int rd = 0; rd < 16; rd++) {
        int idx = rd * 256 + tid;
        int r = idx >> 6, cs = idx & 63;
        int row = m0 + r; if (row >= M) row = M - 1;
        int cl = cs ^ (r & 7);
        ld_lds16(&As[idx * 4], A + (size_t)row * 256 + cl * 4);
    }
    #pragma unroll
    for (int rd = 0; rd < 16; rd++) {
        int idx = rd * 256 + tid;
        int n = idx >> 5, cs = idx & 31;
        int cl = cs ^ (n & 7);
        ld_lds16(&Bs[idx * 8], Bt + (size_t)n * 256 + cl * 8);
    }
    __syncthreads();

    floatx4 acc[8];
    #pragma unroll
    for (int nt = 0; nt < 8; nt++)
        acc[nt] = (floatx4){0.f, 0.f, 0.f, 0.f};

    const int wr = wave * 16 + lrow;
    #pragma unroll
    for (int kk = 0; kk < 8; kk++) {
        int c0 = kk * 8 + hh * 2;
        float4 u = *(const float4*)&As[wr * 256 + ((c0    ) ^ (wr & 7)) * 4];
        float4 v = *(const float4*)&As[wr * 256 + ((c0 + 1) ^ (wr & 7)) * 4];
        short8 afr;
        afr[0] = (short)f2bf(u.x); afr[1] = (short)f2bf(u.y);
        afr[2] = (short)f2bf(u.z); afr[3] = (short)f2bf(u.w);
        afr[4] = (short)f2bf(v.x); afr[5] = (short)f2bf(v.y);
        afr[6] = (short)f2bf(v.z); afr[7] = (short)f2bf(v.w);
        short8 bfr[8];
        #pragma unroll
        for (int nt = 0; nt < 8; nt++) {
            int n = nt * 16 + lrow;
            int c = kk * 4 + hh;
            bfr[nt] = *(const short8*)&Bs[n * 256 + (c ^ (n & 7)) * 8];
        }
        #pragma unroll
        for (int nt = 0; nt < 8; nt++)
            acc[nt] = __builtin_amdgcn_mfma_f32_16x16x32_bf16(
                afr, bfr[nt], acc[nt], 0, 0, 0);
    }

    const int mbase = m0 + wave * 16 + hh * 4;
    float4 dv = *(const float4*)&dinv[mbase];   // dinv padded past N
    float d[4] = {dv.x, dv.y, dv.z, dv.w};
    #pragma unroll
    for (int i = 0; i < 4; i++) {
        int m = mbase + i;
        if (m < M) {
            #pragma unroll
            for (int nt = 0; nt < 8; nt++)
                out[(size_t)m * 128 + nt * 16 + lrow] =
                    f2bf(acc[nt][i] * d[i]);
        } else if (m == M) {               // zero dummy row (was memset)
            #pragma unroll
            for (int nt = 0; nt < 8; nt++)
                out[(size_t)M * 128 + nt * 16 + lrow] = 0;
        }
    }
}

// ------------------------------ GEMM 2 -------------------------------------
// A bf16 [M,128], Bt bf16 [64,128]; out bf16 [M,64] scaled by dinv.
// One-shot template: 32KB LDS. Epilogue zeroes dummy row M.
__global__ __launch_bounds__(256) void gemm2_mfma(
    const ushort_t* __restrict__ A, const ushort_t* __restrict__ Bt,
    const float* __restrict__ dinv, ushort_t* __restrict__ out, int M) {
    __shared__ ushort_t As[64 * 128];   // 16 KB
    __shared__ ushort_t Bs[64 * 128];   // 16 KB
    const int tid = threadIdx.x;
    const int l = tid & 63;
    const int wave = tid >> 6;
    const int lrow = l & 15, hh = l >> 4;
    const int m0 = blockIdx.x * 64;

    #pragma unroll
    for (int rd = 0; rd < 4; rd++) {
        int idx = rd * 256 + tid;
        int r = idx >> 4, cs = idx & 15;
        int row = m0 + r; if (row >= M) row = M - 1;
        int cl = cs ^ (r & 7);
        ld_lds16(&As[idx * 8], A + (size_t)row * 128 + cl * 8);
    }
    #pragma unroll
    for (int rd = 0; rd < 4; rd++) {
        int idx = rd * 256 + tid;
        int n = idx >> 4, cs = idx & 15;
        int cl = cs ^ (n & 7);
        ld_lds16(&Bs[idx * 8], Bt + (size_t)n * 128 + cl * 8);
    }
    __syncthreads();

    floatx4 acc[4];
    #pragma unroll
    for (int nt = 0; nt < 4; nt++)
        acc[nt] = (floatx4){0.f, 0.f, 0.f, 0.f};

    const int wr = wave * 16 + lrow;
    #pragma unroll
    for (int kk = 0; kk < 4; kk++) {
        int c0 = kk * 4 + hh;
        short8 afr = *(const short8*)&As[wr * 128 + (c0 ^ (wr & 7)) * 8];
        short8 bfr[4];
        #pragma unroll
        for (int nt = 0; nt < 4; nt++) {
            int n = nt * 16 + lrow;
            bfr[nt] = *(const short8*)&Bs[n * 128 + (c0 ^ (n & 7)) * 8];
        }
        #pragma unroll
        for (int nt = 0; nt < 4; nt++)
            acc[nt] = __builtin_amdgcn_mfma_f32_16x16x32_bf16(
                afr, bfr[nt], acc[nt], 0, 0, 0);
    }

    const int mbase = m0 + wave * 16 + hh * 4;
    float4 dv = *(const float4*)&dinv[mbase];
    float d[4] = {dv.x, dv.y, dv.z, dv.w};
    #pragma unroll
    for (int i = 0; i < 4; i++) {
        int m = mbase + i;
        if (m < M) {
            #pragma unroll
            for (int nt = 0; nt < 4; nt++)
                out[(size_t)m * 64 + nt * 16 + lrow] =
                    f2bf(acc[nt][i] * d[i]);
        } else if (m == M) {               // zero dummy row (was memset)
            #pragma unroll
            for (int nt = 0; nt < 4; nt++)
                out[(size_t)M * 64 + nt * 16 + lrow] = 0;
        }
    }
}

// ------------------------------ SpMM 1 -------------------------------------
// F=128, bf16 in/out. Multi-edge dwordx4 gather: 16 lanes cover one 256B row,
// 4 edges per load instruction. doff = byte offset of zeroed dummy row.
__global__ __launch_bounds__(256) void spmm_relu128(
    const ushort_t* __restrict__ Mm, const int* __restrict__ rowptr,
    const int* __restrict__ csr, const float* __restrict__ dinv,
    const float* __restrict__ bias, ushort_t* __restrict__ out, int n, int doff) {
    int v = (blockIdx.x * 256 + threadIdx.x) >> 6;
    int lane = threadIdx.x & 63;
    if (v >= n) return;
    int jb = rowptr[v];
    int cntn = rowptr[v + 1] - jb;
    const char* Mb = (const char*)Mm;
    const int slot = lane >> 4;             // which of 4 edges per instr
    const int q = lane & 15;                // column group: bytes q*16 (8 cols)
    const uint_t qb = (uint_t)q * 16;

    float2 a0 = {0.f, 0.f}, a1 = a0, a2 = a0, a3 = a0;
    if (slot == 0) {                        // self row, counted once
        uint4 s = *(const uint4*)(Mb + ((size_t)v << 8) + qb);
        a0 = up2(s.x); a1 = up2(s.y); a2 = up2(s.z); a3 = up2(s.w);
    }

    for (int base = 0; base < cntn; base += 64) {
        int m = cntn - base; if (m > 64) m = 64;
        int roff = (base + lane < cntn) ? (csr[jb + base + lane] << 8) : doff;
        int m4 = (m + 3) & ~3;
        int jj = 0;
        for (; jj + 16 <= m4; jj += 16) {   // 4 x dwordx4 = 16 edges
            uint_t o[4];
            #pragma unroll
            for (int t = 0; t < 4; t++)
                o[t] = (uint_t)__shfl(roff, jj + 4 * t + slot) + qb;
            uint4 p[4];
            #pragma unroll
            for (int t = 0; t < 4; t++) p[t] = *(const uint4*)(Mb + o[t]);
            #pragma unroll
            for (int t = 0; t < 4; t++) {
                float2 f;
                f = up2(p[t].x); a0.x += f.x; a0.y += f.y;
                f = up2(p[t].y); a1.x += f.x; a1.y += f.y;
                f = up2(p[t].z); a2.x += f.x; a2.y += f.y;
                f = up2(p[t].w); a3.x += f.x; a3.y += f.y;
            }
        }
        for (; jj < m4; jj += 4) {          // 1 x dwordx4 = 4 edges
            uint_t o = (uint_t)__shfl(roff, jj + slot) + qb;
            uint4 p = *(const uint4*)(Mb + o);
            float2 f;
            f = up2(p.x); a0.x += f.x; a0.y += f.y;
            f = up2(p.y); a1.x += f.x; a1.y += f.y;
            f = up2(p.z); a2.x += f.x; a2.y += f.y;
            f = up2(p.w); a3.x += f.x; a3.y += f.y;
        }
    }
    float r[8] = {a0.x, a0.y, a1.x, a1.y, a2.x, a2.y, a3.x, a3.y};
    #pragma unroll
    for (int i = 0; i < 8; i++) r[i] += __shfl_xor(r[i], 16);
    #pragma unroll
    for (int i = 0; i < 8; i++) r[i] += __shfl_xor(r[i], 32);
    if (slot == 0) {
        float d = dinv[v];
        float4 bv0 = *(const float4*)&bias[q * 8];
        float4 bv1 = *(const float4*)&bias[q * 8 + 4];
        float o0 = fmaxf(d * r[0] + bv0.x, 0.f);
        float o1 = fmaxf(d * r[1] + bv0.y, 0.f);
        float o2 = fmaxf(d * r[2] + bv0.z, 0.f);
        float o3 = fmaxf(d * r[3] + bv0.w, 0.f);
        float o4 = fmaxf(d * r[4] + bv1.x, 0.f);
        float o5 = fmaxf(d * r[5] + bv1.y, 0.f);
        float o6 = fmaxf(d * r[6] + bv1.z, 0.f);
        float o7 = fmaxf(d * r[7] + bv1.w, 0.f);
        uint4 pk;
        pk.x = pk2bf(o0, o1); pk.y = pk2bf(o2, o3);
        pk.z = pk2bf(o4, o5); pk.w = pk2bf(o6, o7);
        *(uint4*)(out + (size_t)v * 128 + q * 8) = pk;
    }
}

// ------------------------------ SpMM 2 -------------------------------------
// F=64, bf16 in/out. Multi-edge dwordx4 gather: 8 lanes cover one 128B row,
// 8 edges per load instruction.
__global__ __launch_bounds__(256) void spmm_relu64(
    const ushort_t* __restrict__ Mm, const int* __restrict__ rowptr,
    const int* __restrict__ csr, const float* __restrict__ dinv,
    const float* __restrict__ bias, ushort_t* __restrict__ out, int n, int doff) {
    int v = (blockIdx.x * 256 + threadIdx.x) >> 6;
    int lane = threadIdx.x & 63;
    if (v >= n) return;
    int jb = rowptr[v];
    int cntn = rowptr[v + 1] - jb;
    const char* Mb = (const char*)Mm;
    const int slot = lane >> 3;             // which of 8 edges per instr
    const int q = lane & 7;                 // column group: bytes q*16 (8 cols)
    const uint_t qb = (uint_t)q * 16;

    float2 a0 = {0.f, 0.f}, a1 = a0, a2 = a0, a3 = a0;
    if (slot == 0) {                        // self row
        uint4 s = *(const uint4*)(Mb + ((size_t)v << 7) + qb);
        a0 = up2(s.x); a1 = up2(s.y); a2 = up2(s.z); a3 = up2(s.w);
    }

    for (int base = 0; base < cntn; base += 64) {
        int m = cntn - base; if (m > 64) m = 64;
        int roff = (base + lane < cntn) ? (csr[jb + base + lane] << 7) : doff;
        int m8 = (m + 7) & ~7;
        int jj = 0;
        for (; jj + 16 <= m8; jj += 16) {   // 2 x dwordx4 = 16 edges
            uint_t o[2];
            #pragma unroll
            for (int t = 0; t < 2; t++)
                o[t] = (uint_t)__shfl(roff, jj + 8 * t + slot) + qb;
            uint4 p[2];
            #pragma unroll
            for (int t = 0; t < 2; t++) p[t] = *(const uint4*)(Mb + o[t]);
            #pragma unroll
            for (int t = 0; t < 2; t++) {
                float2 f;
                f = up2(p[t].x); a0.x += f.x; a0.y += f.y;
                f = up2(p[t].y); a1.x += f.x; a1.y += f.y;
                f = up2(p[t].z); a2.x += f.x; a2.y += f.y;
                f = up2(p[t].w); a3.x += f.x; a3.y += f.y;
            }
        }
        for (; jj < m8; jj += 8) {          // 1 x dwordx4 = 8 edges
            uint_t o = (uint_t)__shfl(roff, jj + slot) + qb;
            uint4 p = *(const uint4*)(Mb + o);
            float2 f;
            f = up2(p.x); a0.x += f.x; a0.y += f.y;
            f = up2(p.y); a1.x += f.x; a1.y += f.y;
            f = up2(p.z); a2.x += f.x; a2.y += f.y;
            f = up2(p.w); a3.x += f.x; a3.y += f.y;
        }
    }
    float r[8] = {a0.x, a0.y, a1.x, a1.y, a2.x, a2.y, a3.x, a3.y};
    #pragma unroll
    for (int i = 0; i < 8; i++) r[i] += __shfl_xor(r[i], 8);
    #pragma unroll
    for (int i = 0; i < 8; i++) r[i] += __shfl_xor(r[i], 16);
    #pragma unroll
    for (int i = 0; i < 8; i++) r[i] += __shfl_xor(r[i], 32);
    if (slot == 0) {
        float d = dinv[v];
        float4 bv0 = *(const float4*)&bias[q * 8];
        float4 bv1 = *(const float4*)&bias[q * 8 + 4];
        float o0 = fmaxf(d * r[0] + bv0.x, 0.f);
        float o1 = fmaxf(d * r[1] + bv0.y, 0.f);
        float o2 = fmaxf(d * r[2] + bv0.z, 0.f);
        float o3 = fmaxf(d * r[3] + bv0.w, 0.f);
        float o4 = fmaxf(d * r[4] + bv1.x, 0.f);
        float o5 = fmaxf(d * r[5] + bv1.y, 0.f);
        float o6 = fmaxf(d * r[6] + bv1.z, 0.f);
        float o7 = fmaxf(d * r[7] + bv1.w, 0.f);
        uint4 pk;
        pk.x = pk2bf(o0, o1); pk.y = pk2bf(o2, o3);
        pk.z = pk2bf(o4, o5); pk.w = pk2bf(o6, o7);
        *(uint4*)(out + (size_t)v * 64 + q * 8) = pk;
    }
}

// ------------------------------ head ---------------------------------------
__global__ __launch_bounds__(256) void head_kernel(
    const ushort_t* __restrict__ h2, const float* __restrict__ Wl,
    const float* __restrict__ bl, float* __restrict__ out, int n) {
    __shared__ float Ws[64 * 10];
    __shared__ float bs[10];
    for (int i = threadIdx.x; i < 640; i += 256) Ws[i] = Wl[i];
    if (threadIdx.x < 10) bs[threadIdx.x] = bl[threadIdx.x];
    __syncthreads();
    int v = blockIdx.x * 256 + threadIdx.x;
    if (v >= n) return;
    float acc[10];
    #pragma unroll
    for (int c = 0; c < 10; c++) acc[c] = bs[c];
    const ushort_t* hrow = &h2[(size_t)v * 64];
    #pragma unroll
    for (int k0 = 0; k0 < 64; k0 += 8) {
        short8 hv = *(const short8*)&hrow[k0];
        #pragma unroll
        for (int kk = 0; kk < 8; kk++) {
            float hf = bf2f((ushort_t)hv[kk]);
            #pragma unroll
            for (int c = 0; c < 10; c++)
                acc[c] += hf * Ws[(k0 + kk) * 10 + c];
        }
    }
    float m = acc[0];
    #pragma unroll
    for (int c = 1; c < 10; c++) m = fmaxf(m, acc[c]);
    float s = 0.f;
    #pragma unroll
    for (int c = 0; c < 10; c++) s += expf(acc[c] - m);
    float lse = logf(s);
    #pragma unroll
    for (int c = 0; c < 10; c++) out[(size_t)v * 10 + c] = acc[c] - m - lse;
}

// ------------------------------ launch -------------------------------------
extern "C" void kernel_launch(void* const* d_in, const int* in_sizes, int n_in,
                              void* d_out, int out_size, void* d_ws, size_t ws_size,
                              hipStream_t stream) {
    const float* x   = (const float*)d_in[0];
    const int*   ei  = (const int*)d_in[1];      // int32 (JAX x64 disabled)
    const float* W1  = (const float*)d_in[2];
    const float* b1  = (const float*)d_in[3];
    const float* W2  = (const float*)d_in[4];
    const float* b2  = (const float*)d_in[5];
    const float* Wl  = (const float*)d_in[6];
    const float* bl  = (const float*)d_in[7];
    float*       out = (float*)d_out;

    const int N = in_sizes[0] / 256;   // 100000
    const int E = in_sizes[1] / 2;     // 1600000
    const int* srcI = ei;
    const int* dstI = ei + E;

    const int NB = (N + 127) >> 7;      // 782 buckets (<= NBMAX)
    const int GB = (E + 4095) / 4096;   // 391 edge blocks, 16 edges/thread
    const int WB = (256 * 128 + 128 * 64 + 255) / 256;  // 160 wcvt blocks
    const int SB = (NB + 255) / 256;    // scan_bucket blocks

    char* ws = (char*)d_ws;
    size_t off = 0;
    auto alloc = [&](size_t bytes) -> void* {
        void* p = ws + off;
        off = (off + bytes + 255) & ~(size_t)255;
        return p;
    };
    int*      histG  = (int*)alloc((size_t)GB * NB * 4);      // ~1.2 MB
    int*      totG   = (int*)alloc((size_t)NB * 4);
    int*      bbase  = (int*)alloc((size_t)(NB + 1) * 4);
    int*      done   = (int*)alloc(256);
    int*      packed = (int*)alloc((size_t)E * 4);            // bucket-grouped edges
    int*      rowptr = (int*)alloc((size_t)(N + 1) * 4);
    float*    dinv   = (float*)alloc((size_t)(N + 128) * 4);  // padded: epilogue float4
    int*      csr    = (int*)alloc((size_t)E * 4);
    ushort_t* W1t    = (ushort_t*)alloc((size_t)128 * 256 * 2);
    ushort_t* W2t    = (ushort_t*)alloc((size_t)64 * 128 * 2);
    ushort_t* bufA   = (ushort_t*)alloc((size_t)(N + 2) * 128 * 2); // M1'/M2' + dummy row
    ushort_t* bufB   = (ushort_t*)alloc((size_t)N * 128 * 2); // h1 / h2 (bf16)

    // ---- atomic-free CSR build (+fused wcvt, +fused totals scan) ----
    hist_kernel<<<GB + WB, 256, 0, stream>>>(dstI, histG, W1, W2, W1t, W2t,
                                             done, E, NB, GB);
    scan_bucket<<<SB, 256, 0, stream>>>(histG, totG, bbase, done, GB, NB, SB);
    scatter_kernel<<<GB, 256, 0, stream>>>(srcI, dstI, histG, bbase, packed, E, NB);
    bucket_csr<<<NB, 256, 0, stream>>>(packed, bbase, rowptr, csr, dinv, N, NB);

    const int gblk = (N + 63) / 64;    // 64 rows per block
    // layer 1 (gemm1 epilogue zeroes dummy row N)
    gemm1_mfma<<<gblk, 256, 0, stream>>>(x, W1t, dinv, bufA, N);
    spmm_relu128<<<(N + 3) / 4, 256, 0, stream>>>(bufA, rowptr, csr, dinv, b1, bufB, N, N << 8);
    // layer 2 (gemm2 epilogue zeroes dummy row N)
    gemm2_mfma<<<gblk, 256, 0, stream>>>(bufB, W2t, dinv, bufA, N);
    spmm_relu64<<<(N + 3) / 4, 256, 0, stream>>>(bufA, rowptr, csr, dinv, b2, bufB, N, N << 7);
    // head
    head_kernel<<<(N + 255) / 256, 256, 0, stream>>>(bufB, Wl, bl, out, N);
}

// Round 9
// 357.831 us; speedup vs baseline: 1.1300x; 1.0017x over previous
//
#include <hip/hip_runtime.h>

// ---------------------------------------------------------------------------
// GCN, bf16 data-path.
// R17: persistent-block gemm1. The one-shot version re-staged B (64KB,
//   identical across blocks) 1563x = 100MB L2 traffic, and at 1 block/CU the
//   stage->barrier->compute sequence was fully exposed per block (~10us/block
//   observed vs ~2us model). Now: grid=512, each block stages B ONCE, then
//   loops strided 32-row A-tiles with double-buffered A (2x32KB + 64KB B =
//   128KB LDS): stage tile i+1 before computing tile i; barrier after compute
//   drains loads that had the whole compute to land. No inter-block sync.
// R16 calibrations kept: launch overhead ~1.4us/op; wcvt-in-hist,
//   scan_tot-in-scan_bucket, epilogue dummy-row zeroing (gemm1's moved to a
//   one-time block-0 write). spmm128 FETCH=190MB == compulsory 8-XCD minimum.
// ---------------------------------------------------------------------------

typedef unsigned short ushort_t;
typedef unsigned int uint_t;
typedef __attribute__((ext_vector_type(8))) short short8;
typedef __attribute__((ext_vector_type(4))) float floatx4;

static __device__ __forceinline__ ushort_t f2bf(float f) {
    union { float f; uint_t u; } c; c.f = f;
    return (ushort_t)((c.u + 0x8000u) >> 16);
}
static __device__ __forceinline__ float bf2f(ushort_t h) {
    union { uint_t u; float f; } c; c.u = ((uint_t)h) << 16;
    return c.f;
}
static __device__ __forceinline__ float2 up2(uint_t p) {
    union { uint_t u; float f; } lo, hi;
    lo.u = p << 16; hi.u = p & 0xffff0000u;
    return make_float2(lo.f, hi.f);
}
static __device__ __forceinline__ uint_t pk2bf(float a, float b) {
    return ((uint_t)f2bf(b) << 16) | (uint_t)f2bf(a);
}
// async global->LDS, 16B per lane; LDS dst = wave-uniform base + lane*16.
static __device__ __forceinline__ void ld_lds16(void* lds, const void* g) {
    __builtin_amdgcn_global_load_lds(
        (const __attribute__((address_space(1))) unsigned int*)g,
        (__attribute__((address_space(3))) unsigned int*)lds, 16, 0, 0);
}

// ------------------------- CSR build (atomic-free) -------------------------
// bucket = dst >> 7  (128 nodes per bucket).  N=100000 -> NB=782 <= NBMAX.
#define NBMAX 800
#define ECAP  4096   // max edges per bucket held in LDS (mean 2046, sigma ~45)

// P1: per-block LDS histogram over buckets (blocks < GB); weight transpose +
// bf16 convert (blocks >= GB). Block GB thread 0 zeroes the done-counter.
__global__ __launch_bounds__(256) void hist_kernel(
    const int* __restrict__ dst, int* __restrict__ histG,
    const float* __restrict__ W1, const float* __restrict__ W2,
    ushort_t* __restrict__ W1t, ushort_t* __restrict__ W2t,
    int* __restrict__ done, int E, int NB, int GB) {
    if ((int)blockIdx.x >= GB) {          // ---- fused wcvt2 ----
        if ((int)blockIdx.x == GB && threadIdx.x == 0) *done = 0;
        int i = ((int)blockIdx.x - GB) * 256 + threadIdx.x;
        if (i < 256 * 128) {
            int k = i / 128, n = i % 128;
            W1t[n * 256 + k] = f2bf(W1[i]);
        }
        int j = i - 256 * 128;
        if (j >= 0 && j < 128 * 64) {
            int k = j / 64, n = j % 64;
            W2t[n * 128 + k] = f2bf(W2[j]);
        }
        return;
    }
    __shared__ int h[NBMAX];
    for (int i = threadIdx.x; i < NB; i += 256) h[i] = 0;
    __syncthreads();
    int i16 = (blockIdx.x * 256 + threadIdx.x) * 16;
    if (i16 + 15 < E) {
        #pragma unroll
        for (int u = 0; u < 4; u++) {
            int4 d = *(const int4*)(dst + i16 + u * 4);
            atomicAdd(&h[d.x >> 7], 1);
            atomicAdd(&h[d.y >> 7], 1);
            atomicAdd(&h[d.z >> 7], 1);
            atomicAdd(&h[d.w >> 7], 1);
        }
    } else {
        for (int e = i16; e < E; e++) atomicAdd(&h[dst[e] >> 7], 1);
    }
    __syncthreads();
    int* outp = histG + (size_t)blockIdx.x * NB;   // [blk][b], coalesced
    for (int i = threadIdx.x; i < NB; i += 256) outp[i] = h[i];
}

// S1+S2 fused: per-bucket exclusive scan across blocks (thread-per-bucket,
// coalesced, 16-deep ILP) + LAST-arriving block scans bucket totals -> bbase.
__global__ __launch_bounds__(256) void scan_bucket(
    int* __restrict__ histG, int* __restrict__ totG, int* __restrict__ bbase,
    int* __restrict__ done, int GB, int NB, int nblk) {
    __shared__ int isLast;
    __shared__ int s[256];
    int b = blockIdx.x * 256 + threadIdx.x;
    if (b < NB) {
        int run = 0;
        int g = 0;
        for (; g + 16 <= GB; g += 16) {
            int vv[16];
            #pragma unroll
            for (int u = 0; u < 16; u++) vv[u] = histG[(size_t)(g + u) * NB + b];
            #pragma unroll
            for (int u = 0; u < 16; u++) {
                histG[(size_t)(g + u) * NB + b] = run;
                run += vv[u];
            }
        }
        for (; g < GB; g++) {
            int v = histG[(size_t)g * NB + b];
            histG[(size_t)g * NB + b] = run;
            run += v;
        }
        totG[b] = run;
    }
    __threadfence();                       // release this thread's totG write
    __syncthreads();
    if (threadIdx.x == 0)
        isLast = (atomicAdd(done, 1) == nblk - 1);
    __syncthreads();
    if (!isLast) return;
    __threadfence();                       // acquire other blocks' totG
    int running = 0;
    int nch = (NB + 255) / 256;
    for (int c = 0; c < nch; c++) {
        int j = c * 256 + threadIdx.x;
        int v = (j < NB) ? totG[j] : 0;
        s[threadIdx.x] = v;
        __syncthreads();
        for (int off = 1; off < 256; off <<= 1) {
            int tmp = (threadIdx.x >= off) ? s[threadIdx.x - off] : 0;
            __syncthreads();
            s[threadIdx.x] += tmp;
            __syncthreads();
        }
        if (j < NB) bbase[j] = s[threadIdx.x] - v + running;
        int ctot = s[255];
        __syncthreads();
        running += ctot;
    }
    if (threadIdx.x == 0) bbase[NB] = running;
}

// P3: scatter edges into bucket-grouped order. Same block/edge mapping as P1,
// positions come from LDS atomicAdd on this block's reserved ranges.
// packed = src | (dst&127)<<17   (src < 2^17, dl 7 bits).
__global__ __launch_bounds__(256) void scatter_kernel(
    const int* __restrict__ src, const int* __restrict__ dst,
    const int* __restrict__ histG, const int* __restrict__ bbase,
    int* __restrict__ packed, int E, int NB) {
    __shared__ int lbase[NBMAX];
    const int* row = histG + (size_t)blockIdx.x * NB;
    for (int i = threadIdx.x; i < NB; i += 256)
        lbase[i] = bbase[i] + row[i];
    __syncthreads();
    int i16 = (blockIdx.x * 256 + threadIdx.x) * 16;
    if (i16 + 15 < E) {
        #pragma unroll
        for (int u = 0; u < 4; u++) {
            int4 s4 = *(const int4*)(src + i16 + u * 4);
            int4 d4 = *(const int4*)(dst + i16 + u * 4);
            int p;
            p = atomicAdd(&lbase[d4.x >> 7], 1); packed[p] = s4.x | ((d4.x & 127) << 17);
            p = atomicAdd(&lbase[d4.y >> 7], 1); packed[p] = s4.y | ((d4.y & 127) << 17);
            p = atomicAdd(&lbase[d4.z >> 7], 1); packed[p] = s4.z | ((d4.z & 127) << 17);
            p = atomicAdd(&lbase[d4.w >> 7], 1); packed[p] = s4.w | ((d4.w & 127) << 17);
        }
    } else {
        for (int e = i16; e < E; e++) {
            int d = dst[e];
            int p = atomicAdd(&lbase[d >> 7], 1);
            packed[p] = src[e] | ((d & 127) << 17);
        }
    }
}

// P4: one block per bucket. Edges to LDS, count 128 node degrees (dinv fused),
// 128-wide scan -> rowptr, second pass -> csr. rowptr[N]=E falls out of the
// last bucket (nodes >= N have zero count).
__global__ __launch_bounds__(256) void bucket_csr(
    const int* __restrict__ packed, const int* __restrict__ bbase,
    int* __restrict__ rowptr, int* __restrict__ csr,
    float* __restrict__ dinv, int N, int NB) {
    __shared__ int ebuf[ECAP];
    __shared__ int cnt[128];
    __shared__ int pl[128];
    __shared__ int s[256];
    const int b = blockIdx.x;
    const int t = threadIdx.x;
    const int lo = bbase[b];
    const int hi = bbase[b + 1];
    int m = hi - lo;
    if (m > ECAP) m = ECAP;   // statistically unreachable (+45 sigma)
    for (int i = t; i < m; i += 256) ebuf[i] = packed[lo + i];
    if (t < 128) cnt[t] = 0;
    __syncthreads();
    for (int i = t; i < m; i += 256) atomicAdd(&cnt[ebuf[i] >> 17], 1);
    __syncthreads();
    const int node0 = b << 7;
    int c = (t < 128) ? cnt[t] : 0;
    if (t < 128 && node0 + t < N)
        dinv[node0 + t] = rsqrtf((float)(c + 1));   // +1 self loop
    s[t] = c;
    __syncthreads();
    for (int off = 1; off < 256; off <<= 1) {
        int tmp = (t >= off) ? s[t - off] : 0;
        __syncthreads();
        s[t] += tmp;
        __syncthreads();
    }
    int excl = s[t] - c;
    if (t < 128) {
        pl[t] = excl;
        if (node0 + t <= N) rowptr[node0 + t] = lo + excl;
    }
    __syncthreads();
    for (int i = t; i < m; i += 256) {
        int e = ebuf[i];
        int p = atomicAdd(&pl[e >> 17], 1);
        csr[lo + p] = e & 0x1FFFF;
    }
}

// ------------------------------ GEMM 1 -------------------------------------
// A fp32 [M,256], Bt bf16 [128,256]; out bf16 [M,128] scaled by dinv.
// PERSISTENT: grid=512 (<=1 block/CU resident). Stage B (64KB) once, then
// loop strided 32-row A-tiles, double-buffered (2x32KB): stage tile i+1,
// compute tile i, barrier. Chunk-XOR swizzle c^(r&7) both sides.
// Block 0 zeroes dummy row M (spmm128 tail) once at start.
__global__ __launch_bounds__(256) void gemm1_mfma(
    const float* __restrict__ A, const ushort_t* __restrict__ Bt,
    const float* __restrict__ dinv, ushort_t* __restrict__ out,
    int M, int T) {
    __shared__ float    As[2][32 * 256];   // 2 x 32 KB
    __shared__ ushort_t Bs[128 * 256];     // 64 KB
    const int tid = threadIdx.x;
    const int l = tid & 63;
    const int wave = tid >> 6;             // wave = N-column block (4 x 32)
    const int lrow = l & 15, hh = l >> 4;

    if (blockIdx.x == 0 && tid < 64)       // zero dummy row M once
        *(uint_t*)(out + (size_t)M * 128 + tid * 2) = 0;

    // stage B: 16 rounds x 256 thr x 16B = 64 KB (row n, 32 chunks/row)
    #pragma unroll
    for (int rd = 0; rd < 16; rd++) {
        int idx = rd * 256 + tid;
        int n = idx >> 5, cs = idx & 31;
        int cl = cs ^ (n & 7);
        ld_lds16(&Bs[idx * 8], Bt + (size_t)n * 256 + cl * 8);
    }

    auto stageA = [&](int buf, int t) {
        int m0 = t * 32;
        #pragma unroll
        for (int rd = 0; rd < 8; rd++) {   // 8 rounds x 256 thr x 16B = 32 KB
            int idx = rd * 256 + tid;
            int r = idx >> 6, cs = idx & 63;
            int row = m0 + r; if (row >= M) row = M - 1;
            int cl = cs ^ (r & 7);
            ld_lds16(&As[buf][idx * 4], A + (size_t)row * 256 + cl * 4);
        }
    };

    const int stride = gridDim.x;
    int t0 = blockIdx.x;
    if (t0 >= T) return;
    stageA(0, t0);
    __syncthreads();

    int buf = 0;
    for (int t = t0; t < T; t += stride) {
        int tn = t + stride;
        if (tn < T) stageA(buf ^ 1, tn);   // issue next tile's loads EARLY

        floatx4 acc[2][2];
        #pragma unroll
        for (int mt = 0; mt < 2; mt++)
            #pragma unroll
            for (int nt = 0; nt < 2; nt++)
                acc[mt][nt] = (floatx4){0.f, 0.f, 0.f, 0.f};

        #pragma unroll
        for (int kk = 0; kk < 8; kk++) {
            short8 afr[2];
            #pragma unroll
            for (int mt = 0; mt < 2; mt++) {
                int r = mt * 16 + lrow;
                int c0 = kk * 8 + hh * 2;
                float4 u = *(const float4*)&As[buf][r * 256 + ((c0    ) ^ (r & 7)) * 4];
                float4 v = *(const float4*)&As[buf][r * 256 + ((c0 + 1) ^ (r & 7)) * 4];
                short8 tt;
                tt[0] = (short)f2bf(u.x); tt[1] = (short)f2bf(u.y);
                tt[2] = (short)f2bf(u.z); tt[3] = (short)f2bf(u.w);
                tt[4] = (short)f2bf(v.x); tt[5] = (short)f2bf(v.y);
                tt[6] = (short)f2bf(v.z); tt[7] = (short)f2bf(v.w);
                afr[mt] = tt;
            }
            short8 bfr[2];
            #pragma unroll
            for (int nt = 0; nt < 2; nt++) {
                int n = wave * 32 + nt * 16 + lrow;
                int c = kk * 4 + hh;
                bfr[nt] = *(const short8*)&Bs[n * 256 + (c ^ (n & 7)) * 8];
            }
            #pragma unroll
            for (int mt = 0; mt < 2; mt++)
                #pragma unroll
                for (int nt = 0; nt < 2; nt++)
                    acc[mt][nt] = __builtin_amdgcn_mfma_f32_16x16x32_bf16(
                        afr[mt], bfr[nt], acc[mt][nt], 0, 0, 0);
        }

        const int m0 = t * 32;
        #pragma unroll
        for (int mt = 0; mt < 2; mt++) {
            int mbase = m0 + mt * 16 + hh * 4;
            float4 dv = *(const float4*)&dinv[mbase];   // dinv padded past N
            float d[4] = {dv.x, dv.y, dv.z, dv.w};
            #pragma unroll
            for (int i = 0; i < 4; i++) {
                int m = mbase + i;
                if (m < M) {
                    #pragma unroll
                    for (int nt = 0; nt < 2; nt++)
                        out[(size_t)m * 128 + wave * 32 + nt * 16 + lrow] =
                            f2bf(acc[mt][nt][i] * d[i]);
                }
            }
        }
        __syncthreads();   // drains next-tile loads (had full compute to land)
        buf ^= 1;
    }
}

// ------------------------------ GEMM 2 -------------------------------------
// A bf16 [M,128], Bt bf16 [64,128]; out bf16 [M,64] scaled by dinv.
// One-shot template: 32KB LDS. Epilogue zeroes dummy row M.
__global__ __launch_bounds__(256) void gemm2_mfma(
    const ushort_t* __restrict__ A, const ushort_t* __restrict__ Bt,
    const float* __restrict__ dinv, ushort_t* __restrict__ out, int M) {
    __shared__ ushort_t As[64 * 128];   // 16 KB
    __shared__ ushort_t Bs[64 * 128];   // 16 KB
    const int tid = threadIdx.x;
    const int l = tid & 63;
    const int wave = tid >> 6;
    const int lrow = l & 15, hh = l >> 4;
    const int m0 = blockIdx.x * 64;

    #pragma unroll
    for (int rd = 0; rd < 4; rd++) {
        int idx = rd * 256 + tid;
        int r = idx >> 4, cs = idx & 15;
        int row = m0 + r; if (row >= M) row = M - 1;
        int cl = cs ^ (r & 7);
        ld_lds16(&As[idx * 8], A + (size_t)row * 128 + cl * 8);
    }
    #pragma unroll
    for (int rd = 0; rd < 4; rd++) {
        int idx = rd * 256 + tid;
        int n = idx >> 4, cs = idx & 15;
        int cl = cs ^ (n & 7);
        ld_lds16(&Bs[idx * 8], Bt + (size_t)n * 128 + cl * 8);
    }
    __syncthreads();

    floatx4 acc[4];
    #pragma unroll
    for (int nt = 0; nt < 4; nt++)
        acc[nt] = (floatx4){0.f, 0.f, 0.f, 0.f};

    const int wr = wave * 16 + lrow;
    #pragma unroll
    for (int kk = 0; kk < 4; kk++) {
        int c0 = kk * 4 + hh;
        short8 afr = *(const short8*)&As[wr * 128 + (c0 ^ (wr & 7)) * 8];
        short8 bfr[4];
        #pragma unroll
        for (int nt = 0; nt < 4; nt++) {
            int n = nt * 16 + lrow;
            bfr[nt] = *(const short8*)&Bs[n * 128 + (c0 ^ (n & 7)) * 8];
        }
        #pragma unroll
        for (int nt = 0; nt < 4; nt++)
            acc[nt] = __builtin_amdgcn_mfma_f32_16x16x32_bf16(
                afr, bfr[nt], acc[nt], 0, 0, 0);
    }

    const int mbase = m0 + wave * 16 + hh * 4;
    float4 dv = *(const float4*)&dinv[mbase];
    float d[4] = {dv.x, dv.y, dv.z, dv.w};
    #pragma unroll
    for (int i = 0; i < 4; i++) {
        int m = mbase + i;
        if (m < M) {
            #pragma unroll
            for (int nt = 0; nt < 4; nt++)
                out[(size_t)m * 64 + nt * 16 + lrow] =
                    f2bf(acc[nt][i] * d[i]);
        } else if (m == M) {               // zero dummy row (was memset)
            #pragma unroll
            for (int nt = 0; nt < 4; nt++)
                out[(size_t)M * 64 + nt * 16 + lrow] = 0;
        }
    }
}

// ------------------------------ SpMM 1 -------------------------------------
// F=128, bf16 in/out. Multi-edge dwordx4 gather: 16 lanes cover one 256B row,
// 4 edges per load instruction. doff = byte offset of zeroed dummy row.
__global__ __launch_bounds__(256) void spmm_relu128(
    const ushort_t* __restrict__ Mm, const int* __restrict__ rowptr,
    const int* __restrict__ csr, const float* __restrict__ dinv,
    const float* __restrict__ bias, ushort_t* __restrict__ out, int n, int doff) {
    int v = (blockIdx.x * 256 + threadIdx.x) >> 6;
    int lane = threadIdx.x & 63;
    if (v >= n) return;
    int jb = rowptr[v];
    int cntn = rowptr[v + 1] - jb;
    const char* Mb = (const char*)Mm;
    const int slot = lane >> 4;             // which of 4 edges per instr
    const int q = lane & 15;                // column group: bytes q*16 (8 cols)
    const uint_t qb = (uint_t)q * 16;

    float2 a0 = {0.f, 0.f}, a1 = a0, a2 = a0, a3 = a0;
    if (slot == 0) {                        // self row, counted once
        uint4 s = *(const uint4*)(Mb + ((size_t)v << 8) + qb);
        a0 = up2(s.x); a1 = up2(s.y); a2 = up2(s.z); a3 = up2(s.w);
    }

    for (int base = 0; base < cntn; base += 64) {
        int m = cntn - base; if (m > 64) m = 64;
        int roff = (base + lane < cntn) ? (csr[jb + base + lane] << 8) : doff;
        int m4 = (m + 3) & ~3;
        int jj = 0;
        for (; jj + 16 <= m4; jj += 16) {   // 4 x dwordx4 = 16 edges
            uint_t o[4];
            #pragma unroll
            for (int t = 0; t < 4; t++)
                o[t] = (uint_t)__shfl(roff, jj + 4 * t + slot) + qb;
            uint4 p[4];
            #pragma unroll
            for (int t = 0; t < 4; t++) p[t] = *(const uint4*)(Mb + o[t]);
            #pragma unroll
            for (int t = 0; t < 4; t++) {
                float2 f;
                f = up2(p[t].x); a0.x += f.x; a0.y += f.y;
                f = up2(p[t].y); a1.x += f.x; a1.y += f.y;
                f = up2(p[t].z); a2.x += f.x; a2.y += f.y;
                f = up2(p[t].w); a3.x += f.x; a3.y += f.y;
            }
        }
        for (; jj < m4; jj += 4) {          // 1 x dwordx4 = 4 edges
            uint_t o = (uint_t)__shfl(roff, jj + slot) + qb;
            uint4 p = *(const uint4*)(Mb + o);
            float2 f;
            f = up2(p.x); a0.x += f.x; a0.y += f.y;
            f = up2(p.y); a1.x += f.x; a1.y += f.y;
            f = up2(p.z); a2.x += f.x; a2.y += f.y;
            f = up2(p.w); a3.x += f.x; a3.y += f.y;
        }
    }
    float r[8] = {a0.x, a0.y, a1.x, a1.y, a2.x, a2.y, a3.x, a3.y};
    #pragma unroll
    for (int i = 0; i < 8; i++) r[i] += __shfl_xor(r[i], 16);
    #pragma unroll
    for (int i = 0; i < 8; i++) r[i] += __shfl_xor(r[i], 32);
    if (slot == 0) {
        float d = dinv[v];
        float4 bv0 = *(const float4*)&bias[q * 8];
        float4 bv1 = *(const float4*)&bias[q * 8 + 4];
        float o0 = fmaxf(d * r[0] + bv0.x, 0.f);
        float o1 = fmaxf(d * r[1] + bv0.y, 0.f);
        float o2 = fmaxf(d * r[2] + bv0.z, 0.f);
        float o3 = fmaxf(d * r[3] + bv0.w, 0.f);
        float o4 = fmaxf(d * r[4] + bv1.x, 0.f);
        float o5 = fmaxf(d * r[5] + bv1.y, 0.f);
        float o6 = fmaxf(d * r[6] + bv1.z, 0.f);
        float o7 = fmaxf(d * r[7] + bv1.w, 0.f);
        uint4 pk;
        pk.x = pk2bf(o0, o1); pk.y = pk2bf(o2, o3);
        pk.z = pk2bf(o4, o5); pk.w = pk2bf(o6, o7);
        *(uint4*)(out + (size_t)v * 128 + q * 8) = pk;
    }
}

// ------------------------------ SpMM 2 -------------------------------------
// F=64, bf16 in/out. Multi-edge dwordx4 gather: 8 lanes cover one 128B row,
// 8 edges per load instruction.
__global__ __launch_bounds__(256) void spmm_relu64(
    const ushort_t* __restrict__ Mm, const int* __restrict__ rowptr,
    const int* __restrict__ csr, const float* __restrict__ dinv,
    const float* __restrict__ bias, ushort_t* __restrict__ out, int n, int doff) {
    int v = (blockIdx.x * 256 + threadIdx.x) >> 6;
    int lane = threadIdx.x & 63;
    if (v >= n) return;
    int jb = rowptr[v];
    int cntn = rowptr[v + 1] - jb;
    const char* Mb = (const char*)Mm;
    const int slot = lane >> 3;             // which of 8 edges per instr
    const int q = lane & 7;                 // column group: bytes q*16 (8 cols)
    const uint_t qb = (uint_t)q * 16;

    float2 a0 = {0.f, 0.f}, a1 = a0, a2 = a0, a3 = a0;
    if (slot == 0) {                        // self row
        uint4 s = *(const uint4*)(Mb + ((size_t)v << 7) + qb);
        a0 = up2(s.x); a1 = up2(s.y); a2 = up2(s.z); a3 = up2(s.w);
    }

    for (int base = 0; base < cntn; base += 64) {
        int m = cntn - base; if (m > 64) m = 64;
        int roff = (base + lane < cntn) ? (csr[jb + base + lane] << 7) : doff;
        int m8 = (m + 7) & ~7;
        int jj = 0;
        for (; jj + 16 <= m8; jj += 16) {   // 2 x dwordx4 = 16 edges
            uint_t o[2];
            #pragma unroll
            for (int t = 0; t < 2; t++)
                o[t] = (uint_t)__shfl(roff, jj + 8 * t + slot) + qb;
            uint4 p[2];
            #pragma unroll
            for (int t = 0; t < 2; t++) p[t] = *(const uint4*)(Mb + o[t]);
            #pragma unroll
            for (int t = 0; t < 2; t++) {
                float2 f;
                f = up2(p[t].x); a0.x += f.x; a0.y += f.y;
                f = up2(p[t].y); a1.x += f.x; a1.y += f.y;
                f = up2(p[t].z); a2.x += f.x; a2.y += f.y;
                f = up2(p[t].w); a3.x += f.x; a3.y += f.y;
            }
        }
        for (; jj < m8; jj += 8) {          // 1 x dwordx4 = 8 edges
            uint_t o = (uint_t)__shfl(roff, jj + slot) + qb;
            uint4 p = *(const uint4*)(Mb + o);
            float2 f;
            f = up2(p.x); a0.x += f.x; a0.y += f.y;
            f = up2(p.y); a1.x += f.x; a1.y += f.y;
            f = up2(p.z); a2.x += f.x; a2.y += f.y;
            f = up2(p.w); a3.x += f.x; a3.y += f.y;
        }
    }
    float r[8] = {a0.x, a0.y, a1.x, a1.y, a2.x, a2.y, a3.x, a3.y};
    #pragma unroll
    for (int i = 0; i < 8; i++) r[i] += __shfl_xor(r[i], 8);
    #pragma unroll
    for (int i = 0; i < 8; i++) r[i] += __shfl_xor(r[i], 16);
    #pragma unroll
    for (int i = 0; i < 8; i++) r[i] += __shfl_xor(r[i], 32);
    if (slot == 0) {
        float d = dinv[v];
        float4 bv0 = *(const float4*)&bias[q * 8];
        float4 bv1 = *(const float4*)&bias[q * 8 + 4];
        float o0 = fmaxf(d * r[0] + bv0.x, 0.f);
        float o1 = fmaxf(d * r[1] + bv0.y, 0.f);
        float o2 = fmaxf(d * r[2] + bv0.z, 0.f);
        float o3 = fmaxf(d * r[3] + bv0.w, 0.f);
        float o4 = fmaxf(d * r[4] + bv1.x, 0.f);
        float o5 = fmaxf(d * r[5] + bv1.y, 0.f);
        float o6 = fmaxf(d * r[6] + bv1.z, 0.f);
        float o7 = fmaxf(d * r[7] + bv1.w, 0.f);
        uint4 pk;
        pk.x = pk2bf(o0, o1); pk.y = pk2bf(o2, o3);
        pk.z = pk2bf(o4, o5); pk.w = pk2bf(o6, o7);
        *(uint4*)(out + (size_t)v * 64 + q * 8) = pk;
    }
}

// ------------------------------ head ---------------------------------------
__global__ __launch_bounds__(256) void head_kernel(
    const ushort_t* __restrict__ h2, const float* __restrict__ Wl,
    const float* __restrict__ bl, float* __restrict__ out, int n) {
    __shared__ float Ws[64 * 10];
    __shared__ float bs[10];
    for (int i = threadIdx.x; i < 640; i += 256) Ws[i] = Wl[i];
    if (threadIdx.x < 10) bs[threadIdx.x] = bl[threadIdx.x];
    __syncthreads();
    int v = blockIdx.x * 256 + threadIdx.x;
    if (v >= n) return;
    float acc[10];
    #pragma unroll
    for (int c = 0; c < 10; c++) acc[c] = bs[c];
    const ushort_t* hrow = &h2[(size_t)v * 64];
    #pragma unroll
    for (int k0 = 0; k0 < 64; k0 += 8) {
        short8 hv = *(const short8*)&hrow[k0];
        #pragma unroll
        for (int kk = 0; kk < 8; kk++) {
            float hf = bf2f((ushort_t)hv[kk]);
            #pragma unroll
            for (int c = 0; c < 10; c++)
                acc[c] += hf * Ws[(k0 + kk) * 10 + c];
        }
    }
    float m = acc[0];
    #pragma unroll
    for (int c = 1; c < 10; c++) m = fmaxf(m, acc[c]);
    float s = 0.f;
    #pragma unroll
    for (int c = 0; c < 10; c++) s += expf(acc[c] - m);
    float lse = logf(s);
    #pragma unroll
    for (int c = 0; c < 10; c++) out[(size_t)v * 10 + c] = acc[c] - m - lse;
}

// ------------------------------ launch -------------------------------------
extern "C" void kernel_launch(void* const* d_in, const int* in_sizes, int n_in,
                              void* d_out, int out_size, void* d_ws, size_t ws_size,
                              hipStream_t stream) {
    const float* x   = (const float*)d_in[0];
    const int*   ei  = (const int*)d_in[1];      // int32 (JAX x64 disabled)
    const float* W1  = (const float*)d_in[2];
    const float* b1  = (const float*)d_in[3];
    const float* W2  = (const float*)d_in[4];
    const float* b2  = (const float*)d_in[5];
    const float* Wl  = (const float*)d_in[6];
    const float* bl  = (const float*)d_in[7];
    float*       out = (float*)d_out;

    const int N = in_sizes[0] / 256;   // 100000
    const int E = in_sizes[1] / 2;     // 1600000
    const int* srcI = ei;
    const int* dstI = ei + E;

    const int NB = (N + 127) >> 7;      // 782 buckets (<= NBMAX)
    const int GB = (E + 4095) / 4096;   // 391 edge blocks, 16 edges/thread
    const int WB = (256 * 128 + 128 * 64 + 255) / 256;  // 160 wcvt blocks
    const int SB = (NB + 255) / 256;    // scan_bucket blocks

    char* ws = (char*)d_ws;
    size_t off = 0;
    auto alloc = [&](size_t bytes) -> void* {
        void* p = ws + off;
        off = (off + bytes + 255) & ~(size_t)255;
        return p;
    };
    int*      histG  = (int*)alloc((size_t)GB * NB * 4);      // ~1.2 MB
    int*      totG   = (int*)alloc((size_t)NB * 4);
    int*      bbase  = (int*)alloc((size_t)(NB + 1) * 4);
    int*      done   = (int*)alloc(256);
    int*      packed = (int*)alloc((size_t)E * 4);            // bucket-grouped edges
    int*      rowptr = (int*)alloc((size_t)(N + 1) * 4);
    float*    dinv   = (float*)alloc((size_t)(N + 128) * 4);  // padded: epilogue float4
    int*      csr    = (int*)alloc((size_t)E * 4);
    ushort_t* W1t    = (ushort_t*)alloc((size_t)128 * 256 * 2);
    ushort_t* W2t    = (ushort_t*)alloc((size_t)64 * 128 * 2);
    ushort_t* bufA   = (ushort_t*)alloc((size_t)(N + 2) * 128 * 2); // M1'/M2' + dummy row
    ushort_t* bufB   = (ushort_t*)alloc((size_t)N * 128 * 2); // h1 / h2 (bf16)

    // ---- atomic-free CSR build (+fused wcvt, +fused totals scan) ----
    hist_kernel<<<GB + WB, 256, 0, stream>>>(dstI, histG, W1, W2, W1t, W2t,
                                             done, E, NB, GB);
    scan_bucket<<<SB, 256, 0, stream>>>(histG, totG, bbase, done, GB, NB, SB);
    scatter_kernel<<<GB, 256, 0, stream>>>(srcI, dstI, histG, bbase, packed, E, NB);
    bucket_csr<<<NB, 256, 0, stream>>>(packed, bbase, rowptr, csr, dinv, N, NB);

    // layer 1: persistent gemm1 (zeroes dummy row N itself)
    const int T1 = (N + 31) / 32;      // 3125 32-row tiles
    gemm1_mfma<<<512, 256, 0, stream>>>(x, W1t, dinv, bufA, N, T1);
    spmm_relu128<<<(N + 3) / 4, 256, 0, stream>>>(bufA, rowptr, csr, dinv, b1, bufB, N, N << 8);
    // layer 2 (gemm2 epilogue zeroes dummy row N)
    const int gblk = (N + 63) / 64;
    gemm2_mfma<<<gblk, 256, 0, stream>>>(bufB, W2t, dinv, bufA, N);
    spmm_relu64<<<(N + 3) / 4, 256, 0, stream>>>(bufA, rowptr, csr, dinv, b2, bufB, N, N << 7);
    // head
    head_kernel<<<(N + 255) / 256, 256, 0, stream>>>(bufB, Wl, bl, out, N);
}